// Round 12
// baseline (353.113 us; speedup 1.0000x reference)
//
#include <hip/hip_runtime.h>
#include <math.h>

#define N_NODES 100000
#define N_EDGES 1600000
#define FEAT 128
#define NBUCKET 391   // ceil(N_NODES/256)
#define BCAP 5120     // max edges per 256-node bucket (mean 4096)

typedef __attribute__((ext_vector_type(8))) _Float16 half8;
typedef __attribute__((ext_vector_type(4))) float floatx4;

__device__ inline half8 h8max(half8 a, half8 b) {
    return __builtin_elementwise_max(a, b);   // v_pk_max_f16 x4
}
__device__ inline half8 nt_load_h8(const _Float16* p) {
    return __builtin_nontemporal_load((const half8*)p);
}
__device__ inline void nt_store_h8(_Float16* p, half8 v) {
    __builtin_nontemporal_store(v, (half8*)p);
}

// ---------------------------------------------------------------- merged prep
__global__ __launch_bounds__(256) void prep_all(const float* __restrict__ feat,
                                                _Float16* __restrict__ featH,
                                                const float* __restrict__ W1,
                                                const float* __restrict__ W2a,
                                                const float* __restrict__ W2b,
                                                const float* __restrict__ W3,
                                                _Float16* __restrict__ WT1,
                                                _Float16* __restrict__ WT2a,
                                                _Float16* __restrict__ WT2b,
                                                _Float16* __restrict__ WT3,
                                                int* __restrict__ gcur) {
    const int n4 = (N_NODES * FEAT) / 4;
    int idx = blockIdx.x * 256 + threadIdx.x;
    if (idx < n4) {
        floatx4 v = __builtin_nontemporal_load((const floatx4*)feat + idx);
        union { uint2 u; _Float16 h[4]; } p;
        p.h[0] = (_Float16)v.x; p.h[1] = (_Float16)v.y;
        p.h[2] = (_Float16)v.z; p.h[3] = (_Float16)v.w;
        *(uint2*)(featH + 4 * (size_t)idx) = p.u;
        return;
    }
    int off = idx - n4;
    if (off < 16384) { int n = off / 128, k = off % 128; WT1[off] = (_Float16)W1[k * 128 + n]; return; }
    off -= 16384;
    if (off < 16384) { int n = off / 128, k = off % 128; WT2a[off] = (_Float16)W2a[k * 128 + n]; return; }
    off -= 16384;
    if (off < 16384) { int n = off / 128, k = off % 128; WT2b[off] = (_Float16)W2b[k * 128 + n]; return; }
    off -= 16384;
    if (off < 8192)  { int n = off / 128, k = off % 128; WT3[off] = (_Float16)W3[k * 64 + n]; return; }
    off -= 8192;
    if (off < NBUCKET) gcur[off] = 0;
}

// ---------------------------------------------------------------- bucketed CSR
__global__ __launch_bounds__(512) void bin_edges(const int* __restrict__ src,
                                                 const int* __restrict__ dst,
                                                 uint2* __restrict__ ebuf,
                                                 int* __restrict__ gcur) {
    __shared__ int hist[NBUCKET];
    __shared__ int lbase[NBUCKET];
    __shared__ int cur[NBUCKET];
    __shared__ uint2 tile[4096];

    int t = threadIdx.x;
    int e0 = blockIdx.x * 4096;
    for (int i = t; i < NBUCKET; i += 512) { hist[i] = 0; cur[i] = 0; }
    __syncthreads();

    for (int i = t; i < 4096; i += 512) {
        int e = e0 + i;
        uint2 v; v.x = 0u; v.y = 0xffffffffu;
        if (e < N_EDGES) { v.x = (unsigned)src[e]; v.y = (unsigned)dst[e]; }
        tile[i] = v;
        if (v.y != 0xffffffffu) atomicAdd(&hist[v.y >> 8], 1);
    }
    __syncthreads();

    for (int i = t; i < NBUCKET; i += 512) {
        int c = hist[i];
        lbase[i] = (c > 0) ? atomicAdd(&gcur[i], c) : 0;
    }
    __syncthreads();

    for (int i = t; i < 4096; i += 512) {
        uint2 v = tile[i];
        if (v.y == 0xffffffffu) continue;
        int b = (int)(v.y >> 8);
        int p = lbase[b] + atomicAdd(&cur[b], 1);
        if (p < BCAP) ebuf[(size_t)b * BCAP + p] = v;
    }
}

__global__ __launch_bounds__(512) void scan_buckets(const int* __restrict__ gcur,
                                                    int* __restrict__ bbase,
                                                    int* __restrict__ rowptr) {
    __shared__ int s[512];
    int t = threadIdx.x;
    int v = (t < NBUCKET) ? gcur[t] : 0;
    s[t] = v;
    __syncthreads();
    for (int off = 1; off < 512; off <<= 1) {
        int u = (t >= off) ? s[t - off] : 0;
        __syncthreads();
        s[t] += u;
        __syncthreads();
    }
    if (t < NBUCKET) bbase[t] = s[t] - v;
    if (t == 0) rowptr[N_NODES] = N_EDGES;
}

__global__ __launch_bounds__(256) void bucket_csr(const uint2* __restrict__ ebuf,
                                                  const int* __restrict__ gcur,
                                                  const int* __restrict__ bbase,
                                                  int* __restrict__ rowptr,
                                                  int* __restrict__ esrc) {
    __shared__ int cnt[256];
    __shared__ int off[256];
    __shared__ int astart[256];
    __shared__ int cur[256];

    int b = blockIdx.x, t = threadIdx.x;
    int total = gcur[b]; if (total > BCAP) total = BCAP;
    int base = bbase[b];
    const uint2* eb = ebuf + (size_t)b * BCAP;

    cnt[t] = 0; cur[t] = 0;
    __syncthreads();
    for (int i = t; i < total; i += 256) atomicAdd(&cnt[eb[i].y & 255], 1);
    __syncthreads();

    int v = cnt[t];
    off[t] = v;
    __syncthreads();
    for (int o = 1; o < 256; o <<= 1) {
        int u = (t >= o) ? off[t - o] : 0;
        __syncthreads();
        off[t] += u;
        __syncthreads();
    }
    int excl = off[t] - v;
    int node = (b << 8) + t;
    if (node < N_NODES) rowptr[node] = base + excl;
    astart[t] = base + excl;
    __syncthreads();

    for (int i = t; i < total; i += 256) {
        uint2 e = eb[i];
        int ln = (int)(e.y & 255);
        int p = astart[ln] + atomicAdd(&cur[ln], 1);
        esrc[p] = (int)e.x;
    }
}

// ---------------------------------------------------------------- aggregation
// Each LPE-lane group owns ONE node. Masked chunks of 8 edges -> 8 independent
// row-loads in flight per lane. Packed f16 accumulate. NT store output.
template <int MODE, int D, bool OUTF32, bool BIAS>
__global__ __launch_bounds__(256) void agg_kernel(const _Float16* __restrict__ h,
                                                  const int* __restrict__ rowptr,
                                                  const int* __restrict__ esrc,
                                                  const float* __restrict__ eps,
                                                  int ei,
                                                  const float* __restrict__ bias,
                                                  _Float16* __restrict__ outH,
                                                  float* __restrict__ outF) {
    constexpr int LPE = D / 8;
    constexpr int NPW = 64 / LPE;
    int wid = (int)((blockIdx.x * 256 + threadIdx.x) >> 6);
    int l = threadIdx.x & 63;
    int grp = l / LPE, sl = l % LPE;
    int node = wid * NPW + grp;
    if (node >= N_NODES) return;
    int beg = rowptr[node], end = rowptr[node + 1];
    int deg = end - beg;

    const _Float16 NEUT = (MODE == 0) ? (_Float16)(-65504.0f) : (_Float16)(0.0f);
    half8 neut8 = {NEUT, NEUT, NEUT, NEUT, NEUT, NEUT, NEUT, NEUT};
    half8 acc = neut8;

    for (int e = beg; e < end; e += 8) {
        half8 v[8];
#pragma unroll
        for (int j = 0; j < 8; ++j) {
            int ee = e + j;
            int s = __builtin_nontemporal_load(&esrc[ee < end ? ee : end - 1]);
            v[j] = *(const half8*)(h + (size_t)s * D + sl * 8);
        }
#pragma unroll
        for (int j = 0; j < 8; ++j)
            if (e + j >= end) v[j] = neut8;
        if (MODE == 0) {
            half8 m01 = h8max(v[0], v[1]), m23 = h8max(v[2], v[3]);
            half8 m45 = h8max(v[4], v[5]), m67 = h8max(v[6], v[7]);
            acc = h8max(acc, h8max(h8max(m01, m23), h8max(m45, m67)));
        } else {
            half8 s01 = v[0] + v[1], s23 = v[2] + v[3];
            half8 s45 = v[4] + v[5], s67 = v[6] + v[7];
            acc += (s01 + s23) + (s45 + s67);
        }
    }

    float a[8];
#pragma unroll
    for (int i = 0; i < 8; ++i) a[i] = (float)acc[i];
    if (MODE == 0 && deg == 0) {
#pragma unroll
        for (int i = 0; i < 8; ++i) a[i] = 0.f;
    }
    if (MODE == 2) {
        float inv = 1.f / (float)(deg > 0 ? deg : 1);
#pragma unroll
        for (int i = 0; i < 8; ++i) a[i] *= inv;
    }
    float sc = 1.f + eps[ei];
    half8 self = *(const half8*)(h + (size_t)node * D + sl * 8);
    float o[8];
#pragma unroll
    for (int i = 0; i < 8; ++i) o[i] = fmaf(sc, (float)self[i], a[i]);

    if (OUTF32) {
#pragma unroll
        for (int i = 0; i < 8; ++i)
            if (BIAS) o[i] += bias[sl * 8 + i];
        floatx4* dstp = (floatx4*)(outF + (size_t)node * D + sl * 8);
        floatx4 o0 = {o[0], o[1], o[2], o[3]};
        floatx4 o1 = {o[4], o[5], o[6], o[7]};
        __builtin_nontemporal_store(o0, dstp);
        __builtin_nontemporal_store(o1, dstp + 1);
    } else {
        half8 ov;
#pragma unroll
        for (int i = 0; i < 8; ++i) ov[i] = (_Float16)o[i];
        nt_store_h8(outH + (size_t)node * D + sl * 8, ov);
    }
}

// ---------------------------------------------------------------- MFMA GEMM
// Y = act(X[M][128] @ W[128][BN] (+bias)); X f16 NT-read DIRECT from global,
// W staged in LDS; accumulator bounced through the same LDS for coalesced
// f16 stores. BM=128 rows/block, 4 waves x 32 rows. LDS = BN*256 B.
template <int BN, bool RELU, bool BIAS>
__global__ __launch_bounds__(256) void gemm_mfma(const _Float16* __restrict__ X,
                                                 const _Float16* __restrict__ WT,
                                                 const float* __restrict__ bias,
                                                 _Float16* __restrict__ Yh) {
    __shared__ _Float16 Ws[BN * 128];   // 32 KB (BN=128) / 16 KB (BN=64)
    char* wb = (char*)Ws;

    int t = threadIdx.x;
    int l = t & 63, w = t >> 6;
    int lr = l & 15, lg = l >> 4;
    int rowBase = blockIdx.x * 128;

    // stage W tile: BN rows x 256B
#pragma unroll
    for (int p = 0; p < BN / 16; ++p) {
        int idx = p * 4096 + t * 16;
        int row = idx >> 8, byte = idx & 255;
        *(half8*)(wb + row * 256 + (byte ^ ((row & 7) << 4))) =
            *(const half8*)((const char*)WT + idx);
    }
    __syncthreads();

    constexpr int NCT = BN / 16;
    floatx4 acc[2][NCT];
#pragma unroll
    for (int rt = 0; rt < 2; ++rt)
#pragma unroll
        for (int ct = 0; ct < NCT; ++ct)
#pragma unroll
            for (int r = 0; r < 4; ++r) acc[rt][ct][r] = 0.f;

    const _Float16* xrow[2];
#pragma unroll
    for (int rt = 0; rt < 2; ++rt) {
        int grow = rowBase + w * 32 + rt * 16 + lr;
        xrow[rt] = X + (size_t)(grow < N_NODES ? grow : 0) * 128;
    }

#pragma unroll
    for (int ks = 0; ks < 4; ++ks) {
        half8 a[2];
#pragma unroll
        for (int rt = 0; rt < 2; ++rt)
            a[rt] = nt_load_h8(xrow[rt] + ks * 32 + lg * 8);
#pragma unroll
        for (int ct = 0; ct < NCT; ++ct) {
            int n = ct * 16 + lr;
            half8 b = *(const half8*)(wb + n * 256 + ((ks * 64 + lg * 16) ^ ((n & 7) << 4)));
            acc[0][ct] = __builtin_amdgcn_mfma_f32_16x16x32_f16(a[0], b, acc[0][ct], 0, 0, 0);
            acc[1][ct] = __builtin_amdgcn_mfma_f32_16x16x32_f16(a[1], b, acc[1][ct], 0, 0, 0);
        }
    }

    float bv[NCT];
#pragma unroll
    for (int ct = 0; ct < NCT; ++ct) bv[ct] = BIAS ? bias[ct * 16 + lr] : 0.f;

    // bounce accumulator through Ws (reuse; 128*ROWB == BN*256 bytes)
    constexpr int ROWB = BN * 2;
    __syncthreads();   // all B-reads done
#pragma unroll
    for (int rt = 0; rt < 2; ++rt)
#pragma unroll
        for (int ct = 0; ct < NCT; ++ct)
#pragma unroll
            for (int r = 0; r < 4; ++r) {
                int row = w * 32 + rt * 16 + lg * 4 + r;
                int col = ct * 16 + lr;
                float v = acc[rt][ct][r] + bv[ct];
                if (RELU) v = fmaxf(v, 0.f);
                *(_Float16*)(wb + row * ROWB + ((col * 2) ^ ((row & 7) << 4))) =
                    (_Float16)v;
            }
    __syncthreads();
    {
        int row = t >> 1, hf = t & 1;
        int g2 = rowBase + row;
        if (g2 < N_NODES) {
            char* dstp = (char*)(Yh + (size_t)g2 * BN) + hf * (ROWB / 2);
#pragma unroll
            for (int j = 0; j < ROWB / 32; ++j) {
                int byte = hf * (ROWB / 2) + j * 16;
                half8 v = *(const half8*)(wb + row * ROWB + (byte ^ ((row & 7) << 4)));
                *(half8*)(dstp + j * 16) = v;
            }
        }
    }
}

// ---------------------------------------------------------------- launch
extern "C" void kernel_launch(void* const* d_in, const int* in_sizes, int n_in,
                              void* d_out, int out_size, void* d_ws, size_t ws_size,
                              hipStream_t stream) {
    const float* feat = (const float*)d_in[0];
    const int*   src  = (const int*)d_in[1];
    const int*   dst  = (const int*)d_in[2];
    const float* W1   = (const float*)d_in[3];
    const float* b1   = (const float*)d_in[4];
    const float* W2a  = (const float*)d_in[5];
    const float* b2a  = (const float*)d_in[6];
    const float* W2b  = (const float*)d_in[7];
    const float* b2b  = (const float*)d_in[8];
    const float* W3   = (const float*)d_in[9];
    const float* b3   = (const float*)d_in[10];
    const float* eps  = (const float*)d_in[11];

    const size_t NH = (size_t)N_NODES * FEAT;
    char* base = (char*)d_ws;
    auto alloc = [&](size_t bytes) {
        char* p = base;
        base += (bytes + 255) & ~(size_t)255;
        return p;
    };
    _Float16* featH = (_Float16*)alloc(NH * 2);
    _Float16* hA    = (_Float16*)alloc(NH * 2);
    _Float16* hB    = (_Float16*)alloc(NH * 2);
    _Float16* WT1   = (_Float16*)alloc(128 * 128 * 2);
    _Float16* WT2a  = (_Float16*)alloc(128 * 128 * 2);
    _Float16* WT2b  = (_Float16*)alloc(128 * 128 * 2);
    _Float16* WT3   = (_Float16*)alloc(128 * 64 * 2);
    uint2* ebuf     = (uint2*)alloc((size_t)NBUCKET * BCAP * 8);
    int* rowptr     = (int*)alloc((N_NODES + 1) * 4);
    int* esrc       = (int*)alloc((size_t)N_EDGES * 4);
    int* gcur       = (int*)alloc(NBUCKET * 4);
    int* bbase      = (int*)alloc(NBUCKET * 4);

    // --- merged preps
    const int PREP_ITEMS = (int)(NH / 4) + 16384 * 3 + 8192 + NBUCKET;
    prep_all<<<(PREP_ITEMS + 255) / 256, 256, 0, stream>>>(
        feat, featH, W1, W2a, W2b, W3, WT1, WT2a, WT2b, WT3, gcur);

    // --- bucketed CSR build
    bin_edges<<<(N_EDGES + 4095) / 4096, 512, 0, stream>>>(src, dst, ebuf, gcur);
    scan_buckets<<<1, 512, 0, stream>>>(gcur, bbase, rowptr);
    bucket_csr<<<NBUCKET, 256, 0, stream>>>(ebuf, gcur, bbase, rowptr, esrc);

    const int AGG128_GRID = (N_NODES + 15) / 16;   // NPW=4
    const int AGG64_GRID  = (N_NODES + 31) / 32;   // NPW=8
    const int GEMM_GRID   = (N_NODES + 127) / 128; // 782

    // layer 0: max agg + W1 + relu
    agg_kernel<0, 128, false, false><<<AGG128_GRID, 256, 0, stream>>>(
        featH, rowptr, esrc, eps, 0, nullptr, hB, nullptr);
    gemm_mfma<128, true, true><<<GEMM_GRID, 256, 0, stream>>>(hB, WT1, b1, hA);
    // layer 1: sum agg + W2a + relu
    agg_kernel<1, 128, false, false><<<AGG128_GRID, 256, 0, stream>>>(
        hA, rowptr, esrc, eps, 1, nullptr, hB, nullptr);
    gemm_mfma<128, true, true><<<GEMM_GRID, 256, 0, stream>>>(hB, WT2a, b2a, hA);
    // layer 2: sum agg + W2b + relu
    agg_kernel<1, 128, false, false><<<AGG128_GRID, 256, 0, stream>>>(
        hA, rowptr, esrc, eps, 2, nullptr, hB, nullptr);
    gemm_mfma<128, true, true><<<GEMM_GRID, 256, 0, stream>>>(hB, WT2b, b2b, hA);
    // layer 3 (transform-first): p = hA@W3 (f16), then mean-agg(64) + b3 -> f32
    gemm_mfma<64, false, false><<<GEMM_GRID, 256, 0, stream>>>(hA, WT3, nullptr, hB);
    agg_kernel<2, 64, true, true><<<AGG64_GRID, 256, 0, stream>>>(
        hB, rowptr, esrc, eps, 3, b3, nullptr, (float*)d_out);
}

// Round 13
// 322.772 us; speedup vs baseline: 1.0940x; 1.0940x over previous
//
#include <hip/hip_runtime.h>
#include <math.h>

#define N_NODES 100000
#define N_EDGES 1600000
#define FEAT 128
#define NBUCKET 391   // ceil(N_NODES/256)
#define BCAP 5120     // max edges per 256-node bucket (mean 4096)

typedef __attribute__((ext_vector_type(8))) _Float16 half8;
typedef __attribute__((ext_vector_type(4))) float floatx4;

__device__ inline half8 h8max(half8 a, half8 b) {
    return __builtin_elementwise_max(a, b);   // v_pk_max_f16 x4
}

// ---------------------------------------------------------------- merged prep
__global__ __launch_bounds__(256) void prep_all(const float* __restrict__ feat,
                                                _Float16* __restrict__ featH,
                                                const float* __restrict__ W1,
                                                const float* __restrict__ W2a,
                                                const float* __restrict__ W2b,
                                                const float* __restrict__ W3,
                                                _Float16* __restrict__ WT1,
                                                _Float16* __restrict__ WT2a,
                                                _Float16* __restrict__ WT2b,
                                                _Float16* __restrict__ WT3,
                                                int* __restrict__ gcur) {
    const int n4 = (N_NODES * FEAT) / 4;
    int idx = blockIdx.x * 256 + threadIdx.x;
    if (idx < n4) {
        float4 v = ((const float4*)feat)[idx];
        union { uint2 u; _Float16 h[4]; } p;
        p.h[0] = (_Float16)v.x; p.h[1] = (_Float16)v.y;
        p.h[2] = (_Float16)v.z; p.h[3] = (_Float16)v.w;
        *(uint2*)(featH + 4 * (size_t)idx) = p.u;
        return;
    }
    int off = idx - n4;
    if (off < 16384) { int n = off / 128, k = off % 128; WT1[off] = (_Float16)W1[k * 128 + n]; return; }
    off -= 16384;
    if (off < 16384) { int n = off / 128, k = off % 128; WT2a[off] = (_Float16)W2a[k * 128 + n]; return; }
    off -= 16384;
    if (off < 16384) { int n = off / 128, k = off % 128; WT2b[off] = (_Float16)W2b[k * 128 + n]; return; }
    off -= 16384;
    if (off < 8192)  { int n = off / 128, k = off % 128; WT3[off] = (_Float16)W3[k * 64 + n]; return; }
    off -= 8192;
    if (off < NBUCKET) gcur[off] = 0;
}

// ---------------------------------------------------------------- bucketed CSR
// ebuf entry: packed u32 = src | (dst&255)<<24  (src < 2^17, safe)
__global__ __launch_bounds__(512) void bin_edges(const int* __restrict__ src,
                                                 const int* __restrict__ dst,
                                                 unsigned* __restrict__ ebuf,
                                                 int* __restrict__ gcur) {
    __shared__ int hist[NBUCKET];
    __shared__ int lbase[NBUCKET];
    __shared__ int cur[NBUCKET];
    __shared__ uint2 tile[4096];   // x = packed, y = bucket (0xffffffff invalid)

    int t = threadIdx.x;
    int e0 = blockIdx.x * 4096;
    for (int i = t; i < NBUCKET; i += 512) { hist[i] = 0; cur[i] = 0; }
    __syncthreads();

    for (int i = t; i < 4096; i += 512) {
        int e = e0 + i;
        uint2 v; v.x = 0u; v.y = 0xffffffffu;
        if (e < N_EDGES) {
            unsigned s = (unsigned)src[e], d = (unsigned)dst[e];
            v.x = s | ((d & 255u) << 24);
            v.y = d >> 8;
        }
        tile[i] = v;
        if (v.y != 0xffffffffu) atomicAdd(&hist[v.y], 1);
    }
    __syncthreads();

    for (int i = t; i < NBUCKET; i += 512) {
        int c = hist[i];
        lbase[i] = (c > 0) ? atomicAdd(&gcur[i], c) : 0;
    }
    __syncthreads();

    for (int i = t; i < 4096; i += 512) {
        uint2 v = tile[i];
        if (v.y == 0xffffffffu) continue;
        int b = (int)v.y;
        int p = lbase[b] + atomicAdd(&cur[b], 1);
        if (p < BCAP) ebuf[(size_t)b * BCAP + p] = v.x;
    }
}

__global__ __launch_bounds__(512) void scan_buckets(const int* __restrict__ gcur,
                                                    int* __restrict__ bbase,
                                                    int* __restrict__ rowptr) {
    __shared__ int s[512];
    int t = threadIdx.x;
    int v = (t < NBUCKET) ? gcur[t] : 0;
    s[t] = v;
    __syncthreads();
    for (int off = 1; off < 512; off <<= 1) {
        int u = (t >= off) ? s[t - off] : 0;
        __syncthreads();
        s[t] += u;
        __syncthreads();
    }
    if (t < NBUCKET) bbase[t] = s[t] - v;
    if (t == 0) rowptr[N_NODES] = N_EDGES;
}

__global__ __launch_bounds__(256) void bucket_csr(const unsigned* __restrict__ ebuf,
                                                  const int* __restrict__ gcur,
                                                  const int* __restrict__ bbase,
                                                  int* __restrict__ rowptr,
                                                  int* __restrict__ esrc) {
    __shared__ int cnt[256];
    __shared__ int off[256];
    __shared__ int astart[256];
    __shared__ int cur[256];

    int b = blockIdx.x, t = threadIdx.x;
    int total = gcur[b]; if (total > BCAP) total = BCAP;
    int base = bbase[b];
    const unsigned* eb = ebuf + (size_t)b * BCAP;

    cnt[t] = 0; cur[t] = 0;
    __syncthreads();
    for (int i = t; i < total; i += 256) atomicAdd(&cnt[eb[i] >> 24], 1);
    __syncthreads();

    int v = cnt[t];
    off[t] = v;
    __syncthreads();
    for (int o = 1; o < 256; o <<= 1) {
        int u = (t >= o) ? off[t - o] : 0;
        __syncthreads();
        off[t] += u;
        __syncthreads();
    }
    int excl = off[t] - v;
    int node = (b << 8) + t;
    if (node < N_NODES) rowptr[node] = base + excl;
    astart[t] = base + excl;
    __syncthreads();

    for (int i = t; i < total; i += 256) {
        unsigned e = eb[i];
        int ln = (int)(e >> 24);
        int p = astart[ln] + atomicAdd(&cur[ln], 1);
        esrc[p] = (int)(e & 0x00ffffffu);
    }
}

// ---------------------------------------------------------------- aggregation
// Each LPE-lane group owns ONE node. Masked chunks of 8 edges -> 8 independent
// row-loads in flight per lane. Packed f16 accumulate.
template <int MODE, int D, bool OUTF32, bool BIAS>
__global__ __launch_bounds__(256) void agg_kernel(const _Float16* __restrict__ h,
                                                  const int* __restrict__ rowptr,
                                                  const int* __restrict__ esrc,
                                                  const float* __restrict__ eps,
                                                  int ei,
                                                  const float* __restrict__ bias,
                                                  _Float16* __restrict__ outH,
                                                  float* __restrict__ outF) {
    constexpr int LPE = D / 8;
    constexpr int NPW = 64 / LPE;
    int wid = (int)((blockIdx.x * 256 + threadIdx.x) >> 6);
    int l = threadIdx.x & 63;
    int grp = l / LPE, sl = l % LPE;
    int node = wid * NPW + grp;
    if (node >= N_NODES) return;
    int beg = rowptr[node], end = rowptr[node + 1];
    int deg = end - beg;

    const _Float16 NEUT = (MODE == 0) ? (_Float16)(-65504.0f) : (_Float16)(0.0f);
    half8 neut8 = {NEUT, NEUT, NEUT, NEUT, NEUT, NEUT, NEUT, NEUT};
    half8 acc = neut8;

    for (int e = beg; e < end; e += 8) {
        half8 v[8];
#pragma unroll
        for (int j = 0; j < 8; ++j) {
            int ee = e + j;
            int s = esrc[ee < end ? ee : end - 1];
            v[j] = *(const half8*)(h + (size_t)s * D + sl * 8);
        }
#pragma unroll
        for (int j = 0; j < 8; ++j)
            if (e + j >= end) v[j] = neut8;
        if (MODE == 0) {
            half8 m01 = h8max(v[0], v[1]), m23 = h8max(v[2], v[3]);
            half8 m45 = h8max(v[4], v[5]), m67 = h8max(v[6], v[7]);
            acc = h8max(acc, h8max(h8max(m01, m23), h8max(m45, m67)));
        } else {
            half8 s01 = v[0] + v[1], s23 = v[2] + v[3];
            half8 s45 = v[4] + v[5], s67 = v[6] + v[7];
            acc += (s01 + s23) + (s45 + s67);
        }
    }

    float a[8];
#pragma unroll
    for (int i = 0; i < 8; ++i) a[i] = (float)acc[i];
    if (MODE == 0 && deg == 0) {
#pragma unroll
        for (int i = 0; i < 8; ++i) a[i] = 0.f;
    }
    if (MODE == 2) {
        float inv = 1.f / (float)(deg > 0 ? deg : 1);
#pragma unroll
        for (int i = 0; i < 8; ++i) a[i] *= inv;
    }
    float sc = 1.f + eps[ei];
    half8 self = *(const half8*)(h + (size_t)node * D + sl * 8);
    float o[8];
#pragma unroll
    for (int i = 0; i < 8; ++i) o[i] = fmaf(sc, (float)self[i], a[i]);

    if (OUTF32) {
#pragma unroll
        for (int i = 0; i < 8; ++i)
            if (BIAS) o[i] += bias[sl * 8 + i];
        float4* dstp = (float4*)(outF + (size_t)node * D + sl * 8);
        dstp[0] = make_float4(o[0], o[1], o[2], o[3]);
        dstp[1] = make_float4(o[4], o[5], o[6], o[7]);
    } else {
        half8 ov;
#pragma unroll
        for (int i = 0; i < 8; ++i) ov[i] = (_Float16)o[i];
        *(half8*)(outH + (size_t)node * D + sl * 8) = ov;
    }
}

// ---------------------------------------------------------------- MFMA GEMM
// Y = act(X[M][128] @ W[128][BN] (+bias)); X f16 read DIRECT from global
// (each row exactly once, L2-hit from prior agg write), W staged in LDS,
// accumulator bounced through the SAME LDS region for coalesced f16 stores.
// BM=64 rows/block, 4 waves x 16 rows. LDS = BN*256 B (32KB/16KB).
template <int BN, bool RELU, bool BIAS>
__global__ __launch_bounds__(256) void gemm_mfma(const _Float16* __restrict__ X,
                                                 const _Float16* __restrict__ WT,
                                                 const float* __restrict__ bias,
                                                 _Float16* __restrict__ Yh) {
    __shared__ _Float16 Ws[BN * 128];   // 32 KB (BN=128) / 16 KB (BN=64)
    char* wb = (char*)Ws;

    int t = threadIdx.x;
    int l = t & 63, w = t >> 6;
    int lr = l & 15, lg = l >> 4;
    int rowBase = blockIdx.x * 64;

    // stage W tile: BN rows x 256B
#pragma unroll
    for (int p = 0; p < BN / 16; ++p) {
        int idx = p * 4096 + t * 16;
        int row = idx >> 8, byte = idx & 255;
        *(half8*)(wb + row * 256 + (byte ^ ((row & 7) << 4))) =
            *(const half8*)((const char*)WT + idx);
    }
    __syncthreads();

    constexpr int NCT = BN / 16;
    floatx4 acc[NCT];
#pragma unroll
    for (int ct = 0; ct < NCT; ++ct)
#pragma unroll
        for (int r = 0; r < 4; ++r) acc[ct][r] = 0.f;

    int grow = rowBase + w * 16 + lr;
    int arow = grow < N_NODES ? grow : 0;
    const char* xrow = (const char*)(X + (size_t)arow * 128);

#pragma unroll
    for (int ks = 0; ks < 4; ++ks) {
        half8 a = *(const half8*)(xrow + ks * 64 + lg * 16);
#pragma unroll
        for (int ct = 0; ct < NCT; ++ct) {
            int n = ct * 16 + lr;
            half8 b = *(const half8*)(wb + n * 256 + ((ks * 64 + lg * 16) ^ ((n & 7) << 4)));
            acc[ct] = __builtin_amdgcn_mfma_f32_16x16x32_f16(a, b, acc[ct], 0, 0, 0);
        }
    }

    float bv[NCT];
#pragma unroll
    for (int ct = 0; ct < NCT; ++ct) bv[ct] = BIAS ? bias[ct * 16 + lr] : 0.f;

    // bounce accumulator through Ws (reuse) for coalesced f16 stores
    constexpr int ROWB = BN * 2;
    __syncthreads();   // all B-reads done
#pragma unroll
    for (int ct = 0; ct < NCT; ++ct)
#pragma unroll
        for (int r = 0; r < 4; ++r) {
            int row = w * 16 + lg * 4 + r;
            int col = ct * 16 + lr;
            float v = acc[ct][r] + bv[ct];
            if (RELU) v = fmaxf(v, 0.f);
            *(_Float16*)(wb + row * ROWB + ((col * 2) ^ ((row & 7) << 4))) =
                (_Float16)v;
        }
    __syncthreads();
    {
        int row = t >> 2, q = t & 3;
        int g2 = rowBase + row;
        if (g2 < N_NODES) {
            char* dstp = (char*)(Yh + (size_t)g2 * BN) + q * (ROWB / 4);
#pragma unroll
            for (int j = 0; j < ROWB / 64; ++j) {
                int byte = q * (ROWB / 4) + j * 16;
                half8 v = *(const half8*)(wb + row * ROWB + (byte ^ ((row & 7) << 4)));
                *(half8*)(dstp + j * 16) = v;
            }
        }
    }
}

// ---------------------------------------------------------------- launch
extern "C" void kernel_launch(void* const* d_in, const int* in_sizes, int n_in,
                              void* d_out, int out_size, void* d_ws, size_t ws_size,
                              hipStream_t stream) {
    const float* feat = (const float*)d_in[0];
    const int*   src  = (const int*)d_in[1];
    const int*   dst  = (const int*)d_in[2];
    const float* W1   = (const float*)d_in[3];
    const float* b1   = (const float*)d_in[4];
    const float* W2a  = (const float*)d_in[5];
    const float* b2a  = (const float*)d_in[6];
    const float* W2b  = (const float*)d_in[7];
    const float* b2b  = (const float*)d_in[8];
    const float* W3   = (const float*)d_in[9];
    const float* b3   = (const float*)d_in[10];
    const float* eps  = (const float*)d_in[11];

    const size_t NH = (size_t)N_NODES * FEAT;
    char* base = (char*)d_ws;
    auto alloc = [&](size_t bytes) {
        char* p = base;
        base += (bytes + 255) & ~(size_t)255;
        return p;
    };
    _Float16* featH = (_Float16*)alloc(NH * 2);
    _Float16* hA    = (_Float16*)alloc(NH * 2);
    _Float16* hB    = (_Float16*)alloc(NH * 2);
    _Float16* WT1   = (_Float16*)alloc(128 * 128 * 2);
    _Float16* WT2a  = (_Float16*)alloc(128 * 128 * 2);
    _Float16* WT2b  = (_Float16*)alloc(128 * 128 * 2);
    _Float16* WT3   = (_Float16*)alloc(128 * 64 * 2);
    unsigned* ebuf  = (unsigned*)alloc((size_t)NBUCKET * BCAP * 4);
    int* rowptr     = (int*)alloc((N_NODES + 1) * 4);
    int* esrc       = (int*)alloc((size_t)N_EDGES * 4);
    int* gcur       = (int*)alloc(NBUCKET * 4);
    int* bbase      = (int*)alloc(NBUCKET * 4);

    // --- merged preps
    const int PREP_ITEMS = (int)(NH / 4) + 16384 * 3 + 8192 + NBUCKET;
    prep_all<<<(PREP_ITEMS + 255) / 256, 256, 0, stream>>>(
        feat, featH, W1, W2a, W2b, W3, WT1, WT2a, WT2b, WT3, gcur);

    // --- bucketed CSR build
    bin_edges<<<(N_EDGES + 4095) / 4096, 512, 0, stream>>>(src, dst, ebuf, gcur);
    scan_buckets<<<1, 512, 0, stream>>>(gcur, bbase, rowptr);
    bucket_csr<<<NBUCKET, 256, 0, stream>>>(ebuf, gcur, bbase, rowptr, esrc);

    const int AGG128_GRID = (N_NODES + 15) / 16;   // NPW=4
    const int AGG64_GRID  = (N_NODES + 31) / 32;   // NPW=8
    const int GEMM_GRID   = (N_NODES + 63) / 64;   // 1563

    // layer 0: max agg + W1 + relu
    agg_kernel<0, 128, false, false><<<AGG128_GRID, 256, 0, stream>>>(
        featH, rowptr, esrc, eps, 0, nullptr, hB, nullptr);
    gemm_mfma<128, true, true><<<GEMM_GRID, 256, 0, stream>>>(hB, WT1, b1, hA);
    // layer 1: sum agg + W2a + relu
    agg_kernel<1, 128, false, false><<<AGG128_GRID, 256, 0, stream>>>(
        hA, rowptr, esrc, eps, 1, nullptr, hB, nullptr);
    gemm_mfma<128, true, true><<<GEMM_GRID, 256, 0, stream>>>(hB, WT2a, b2a, hA);
    // layer 2: sum agg + W2b + relu
    agg_kernel<1, 128, false, false><<<AGG128_GRID, 256, 0, stream>>>(
        hA, rowptr, esrc, eps, 2, nullptr, hB, nullptr);
    gemm_mfma<128, true, true><<<GEMM_GRID, 256, 0, stream>>>(hB, WT2b, b2b, hA);
    // layer 3 (transform-first): p = hA@W3 (f16), then mean-agg(64) + b3 -> f32
    gemm_mfma<64, false, false><<<GEMM_GRID, 256, 0, stream>>>(hA, WT3, nullptr, hB);
    agg_kernel<2, 64, true, true><<<AGG64_GRID, 256, 0, stream>>>(
        hB, rowptr, esrc, eps, 3, b3, nullptr, (float*)d_out);
}